// Round 12
// baseline (127.306 us; speedup 1.0000x reference)
//
#include <hip/hip_runtime.h>
#include <hip/hip_bf16.h>
#include <math.h>

// Problem constants (match reference)
#define TT 7
#define BB 512
#define PP 200
#define QQ 64
#define WWH 64
#define WF 256
#define CC 10
#define NN (BB * PP)          // 102400
#define TQ (TT * QQ)          // 448

typedef __attribute__((ext_vector_type(8))) short short8;
typedef __attribute__((ext_vector_type(4))) float f32x4;

static __device__ __forceinline__ unsigned short f2bf(float f) {
    __hip_bfloat16 b = __float2bfloat16(f);   // RNE
    return *reinterpret_cast<unsigned short*>(&b);
}

// Full 16-lane-row sum via rotate-DPP (row_ror:8/4/2/1). Result valid in ALL
// lanes of each 16-lane DPP row. VALU-pipe only.
static __device__ __forceinline__ float dpp_row_reduce16(float v) {
    int x;
    x = __builtin_amdgcn_update_dpp(0, __float_as_int(v), 0x128, 0xf, 0xf, false); // ror:8
    v += __int_as_float(x);
    x = __builtin_amdgcn_update_dpp(0, __float_as_int(v), 0x124, 0xf, 0xf, false); // ror:4
    v += __int_as_float(x);
    x = __builtin_amdgcn_update_dpp(0, __float_as_int(v), 0x122, 0xf, 0xf, false); // ror:2
    v += __int_as_float(x);
    x = __builtin_amdgcn_update_dpp(0, __float_as_int(v), 0x121, 0xf, 0xf, false); // ror:1
    v += __int_as_float(x);
    return v;
}

#define NEG50_OVER_LN2 (-72.13475204444817f)

// ---------------------------------------------------------------------------
// Kernel 1 (MFMA, v3): per-point weight MLP.
// 256 points/block, 2800 blocks, 4 waves.
// v3 change (theory: K1 ~27us vs ~5us floor = exposed s_load chunk-reload of
// 192 uniform w1/b1 floats through the 112-SGPR budget, too little VALU cover):
//   FEATURE-PARALLEL layer 1. thread = (feature-pair fp=tid&31, point-group
//   pg=tid>>5). Each thread vector-loads its 6 weights ONCE (3x float2 ->
//   VGPRs, coalesced across lanes; NO scalar-pipe streaming), then walks its
//   32 points via 16 float4 loads (L1-resident after first lines) and writes
//   packed bf16 h-pairs to the IDENTICAL swizzled Hl layout (b32 writes).
// W2T staging, MFMA section, DPP epilogue: byte-identical to v2.
// ---------------------------------------------------------------------------
__global__ __launch_bounds__(256, 4) void point_weight_kernel(
    const float* __restrict__ diagms,   // [T*N, 2]
    const float* __restrict__ w1,       // [2,64]
    const float* __restrict__ b1,       // [64]
    const float* __restrict__ w2,       // [64,64]
    const float* __restrict__ b2,       // [64]
    const float* __restrict__ w3,       // [64]
    const float* __restrict__ b3,       // [1]
    float* __restrict__ w_out)          // [T*N]
{
    __shared__ unsigned short Hl[256 * 64];    // [point][k] bf16, swizzled
    __shared__ unsigned short W2T[64 * 64];    // [n][k]     bf16, swizzled

    const int tid  = threadIdx.x;
    const int lane = tid & 63;
    const int wv   = tid >> 6;

    // ---- stage W2T = w2^T as bf16, swizzled -------------------------------
    {
        const int n  = tid & 63;
        const int j0 = (tid >> 6) * 16;
#pragma unroll
        for (int jj = 0; jj < 16; ++jj) {
            const int j = j0 + jj;
            const float v = w2[j * WWH + n];
            const int off = n * 64 + ((((j >> 3) ^ (n & 7))) << 3) + (j & 7);
            W2T[off] = f2bf(v);
        }
    }

    // ---- layer 1, feature-parallel: h[p][f0..f0+1] for 32 points ----------
    {
        const int fp = tid & 31;        // feature pair index 0..31
        const int f0 = fp << 1;         // feature 0..62 (even)
        const int pg = tid >> 5;        // point group 0..7 (32 points each)

        // 6 weights via per-lane coalesced vector loads (VGPRs, no s_load)
        const float2 wx = *reinterpret_cast<const float2*>(w1 + f0);        // w1[0][f0..+1]
        const float2 wy = *reinterpret_cast<const float2*>(w1 + WWH + f0);  // w1[1][f0..+1]
        const float2 wb = *reinterpret_cast<const float2*>(b1 + f0);

        // float4 = two consecutive points' (x,y)
        const float4* dv = reinterpret_cast<const float4*>(diagms)
                         + (((size_t)blockIdx.x * 256 + pg * 32) >> 1);

        // slot/offset math: Hl halfword index = p*64 + ((f0>>3)^(p&7))*8 + (f0&7)
        const int fslot = f0 >> 3;      // 16B slot of this feature pair
        const int frem  = f0 & 7;       // within-slot halfword offset (even)

#pragma unroll
        for (int i = 0; i < 16; ++i) {
            const float4 q = dv[i];     // p0=(pg*32+2i): (q.x,q.y); p1: (q.z,q.w)
            const int p0 = pg * 32 + 2 * i;
            const int p1 = p0 + 1;

            const float h00 = fmaxf(fmaf(q.x, wx.x, fmaf(q.y, wy.x, wb.x)), 0.0f);
            const float h01 = fmaxf(fmaf(q.x, wx.y, fmaf(q.y, wy.y, wb.y)), 0.0f);
            const float h10 = fmaxf(fmaf(q.z, wx.x, fmaf(q.w, wy.x, wb.x)), 0.0f);
            const float h11 = fmaxf(fmaf(q.z, wx.y, fmaf(q.w, wy.y, wb.y)), 0.0f);

            const unsigned int pk0 = (unsigned int)f2bf(h00) | ((unsigned int)f2bf(h01) << 16);
            const unsigned int pk1 = (unsigned int)f2bf(h10) | ((unsigned int)f2bf(h11) << 16);

            const int off0 = p0 * 64 + ((fslot ^ (p0 & 7)) << 3) + frem;
            const int off1 = p1 * 64 + ((fslot ^ (p1 & 7)) << 3) + frem;
            *reinterpret_cast<unsigned int*>(&Hl[off0]) = pk0;
            *reinterpret_cast<unsigned int*>(&Hl[off1]) = pk1;
        }
    }

    __syncthreads();   // W2T + H visible to all

    // ---- per-lane constants for epilogue ----------------------------------
    float b2v[4], w3v[4];
#pragma unroll
    for (int nt = 0; nt < 4; ++nt) {
        b2v[nt] = b2[nt * 16 + (lane & 15)];
        w3v[nt] = w3[nt * 16 + (lane & 15)];
    }
    const float b3s = b3[0];

    // ---- B fragments: 2 ksteps x 4 ntiles, reused across all Mtiles -------
    short8 bf[2][4];
#pragma unroll
    for (int s = 0; s < 2; ++s) {
#pragma unroll
        for (int nt = 0; nt < 4; ++nt) {
            const int n = nt * 16 + (lane & 15);
            const int slot = ((lane >> 4) + s * 4) ^ (lane & 7);
            bf[s][nt] = reinterpret_cast<const short8*>(W2T)[n * 8 + slot];
        }
    }

    const int wave_p0 = wv * 64;
    const size_t out_base = (size_t)blockIdx.x * 256;

#pragma unroll 1
    for (int m = 0; m < 4; ++m) {
        f32x4 acc[4];
#pragma unroll
        for (int nt = 0; nt < 4; ++nt) acc[nt] = (f32x4){0.f, 0.f, 0.f, 0.f};

#pragma unroll
        for (int s = 0; s < 2; ++s) {
            const int p = wave_p0 + m * 16 + (lane & 15);
            const int slot = ((lane >> 4) + s * 4) ^ (lane & 7);
            const short8 af = reinterpret_cast<const short8*>(Hl)[p * 8 + slot];
#pragma unroll
            for (int nt = 0; nt < 4; ++nt) {
                acc[nt] = __builtin_amdgcn_mfma_f32_16x16x32_bf16(af, bf[s][nt], acc[nt], 0, 0, 0);
            }
        }

        // ---- epilogue: +b2, relu, dot w3, rotate-DPP 16-lane reduce -------
        float sum0 = 0.f, sum1 = 0.f, sum2 = 0.f, sum3 = 0.f;
#pragma unroll
        for (int nt = 0; nt < 4; ++nt) {
            sum0 = fmaf(fmaxf(acc[nt][0] + b2v[nt], 0.f), w3v[nt], sum0);
            sum1 = fmaf(fmaxf(acc[nt][1] + b2v[nt], 0.f), w3v[nt], sum1);
            sum2 = fmaf(fmaxf(acc[nt][2] + b2v[nt], 0.f), w3v[nt], sum2);
            sum3 = fmaf(fmaxf(acc[nt][3] + b2v[nt], 0.f), w3v[nt], sum3);
        }
        sum0 = dpp_row_reduce16(sum0);
        sum1 = dpp_row_reduce16(sum1);
        sum2 = dpp_row_reduce16(sum2);
        sum3 = dpp_row_reduce16(sum3);

        const int r_sel = lane & 15;
        if (r_sel < 4) {
            const float sv = (r_sel == 0) ? sum0 : (r_sel == 1) ? sum1
                           : (r_sel == 2) ? sum2 : sum3;           // static select
            const float wa = sv + b3s;
            const float wsig = 1.0f / (1.0f + __expf(-wa));
            const int prow = wave_p0 + m * 16 + ((lane >> 4) << 2) + r_sel;
            w_out[out_base + prow] = wsig;
        }
    }
}

// ---------------------------------------------------------------------------
// Kernel 2 (v2): gaussian rep * weight, mean-pool per segment. (unchanged)
// ---------------------------------------------------------------------------
__global__ __launch_bounds__(256) void rep_pool_kernel(
    const float* __restrict__ diagms,   // [T*N, 2]
    const float* __restrict__ theta,    // [Q,2]
    const float* __restrict__ w_in,     // [T*N]
    float* __restrict__ pooled)         // [B, T*Q]
{
    const int bid = blockIdx.x;         // t*B + b
    const int t = bid >> 9;             // / 512
    const int b = bid & (BB - 1);       // % 512
    const int tid = threadIdx.x;

    __shared__ float4 pxyw[PP];

    if (tid < PP) {
        const int n = t * NN + b * PP + tid;
        const float2 d = reinterpret_cast<const float2*>(diagms)[n];
        float4 v;
        v.x = d.x;
        v.y = d.y;
        v.z = w_in[n];
        v.w = 0.0f;
        pxyw[tid] = v;
    }
    __syncthreads();

    const int q = tid & (QQ - 1);
    const int g = tid >> 6;             // 0..3, uniform per wave
    const float2 th = reinterpret_cast<const float2*>(theta)[q];
    const float tx = th.x;
    const float ty = th.y;

    float acc = 0.0f;
    const int p0 = g * (PP / 4);
#pragma unroll 5
    for (int p = p0; p < p0 + PP / 4; ++p) {
        const float4 v = pxyw[p];       // broadcast ds_read_b128
        const float dx = v.x - tx;
        const float dy = v.y - ty;
        acc = fmaf(v.z, exp2f(fmaf(dx, dx, dy * dy) * NEG50_OVER_LN2), acc);
    }

    __shared__ float part[4][QQ];
    part[g][q] = acc;
    __syncthreads();

    if (tid < QQ) {
        const float s = (part[0][tid] + part[1][tid]) + (part[2][tid] + part[3][tid]);
        pooled[b * TQ + t * QQ + tid] = s * (1.0f / (float)PP);
    }
}

// ---------------------------------------------------------------------------
// Kernel 3 (v3): rho MLP, latency-pipelined + TLP. (unchanged)
// ---------------------------------------------------------------------------
#define K3_ROWS 2
__global__ __launch_bounds__(1024, 4) void rho_kernel(
    const float* __restrict__ pooled,   // [B, T*Q]
    const float* __restrict__ r1,       // [448,256]
    const float* __restrict__ rb1,      // [256]
    const float* __restrict__ r2,       // [256,256]
    const float* __restrict__ rb2,      // [256]
    const float* __restrict__ r3,       // [256,10]
    const float* __restrict__ rb3,      // [10]
    float* __restrict__ out)            // [B, C]
{
    const int b0  = blockIdx.x * K3_ROWS;
    const int tid = threadIdx.x;        // 0..1023
    const int k   = tid & (WF - 1);     // feature 0..255
    const int g   = tid >> 8;           // reduction group 0..3

    __shared__ float tp[K3_ROWS * TQ];  // 896 floats
    __shared__ float z1[K3_ROWS][WF];
    __shared__ float z2[K3_ROWS][WF];
    __shared__ float part[4][K3_ROWS][WF];
    __shared__ float red[8][CC];

    // ---- stage the 2 topo rows (coalesced) --------------------------------
    if (tid < K3_ROWS * TQ) tp[tid] = pooled[(size_t)b0 * TQ + tid];
    __syncthreads();

    // ---- layer 1: 448-deep, split 4x112, 8-wide double-buffered -----------
    {
        float acc0 = 0.0f, acc1 = 0.0f;
        const float* r1c = r1 + k;
        const int ibase = g * (TQ / 4);              // 112 per group
        float rv0[8], rv1[8];
#pragma unroll
        for (int e = 0; e < 8; ++e) rv0[e] = r1c[(ibase + e) * WF];
#pragma unroll 1
        for (int i0 = ibase; i0 < ibase + TQ / 4; i0 += 16) {
#pragma unroll
            for (int e = 0; e < 8; ++e) rv1[e] = r1c[(i0 + 8 + e) * WF];
#pragma unroll
            for (int e = 0; e < 8; ++e) {
                acc0 = fmaf(tp[i0 + e],      rv0[e], acc0);
                acc1 = fmaf(tp[TQ + i0 + e], rv0[e], acc1);
            }
            if (i0 + 16 < ibase + TQ / 4) {
#pragma unroll
                for (int e = 0; e < 8; ++e) rv0[e] = r1c[(i0 + 16 + e) * WF];
            }
#pragma unroll
            for (int e = 0; e < 8; ++e) {
                acc0 = fmaf(tp[i0 + 8 + e],      rv1[e], acc0);
                acc1 = fmaf(tp[TQ + i0 + 8 + e], rv1[e], acc1);
            }
        }
        part[g][0][k] = acc0;
        part[g][1][k] = acc1;
    }
    __syncthreads();
    if (tid < 2 * WF) {
        const int r = tid >> 8;         // row 0/1
        const int kk = tid & (WF - 1);
        z1[r][kk] = fmaxf(part[0][r][kk] + part[1][r][kk] +
                          part[2][r][kk] + part[3][r][kk] + rb1[kk], 0.0f);
    }
    __syncthreads();

    // ---- layer 2: 256-deep, split 4x64 ------------------------------------
    {
        float acc0 = 0.0f, acc1 = 0.0f;
        const float* r2c = r2 + k;
        const int ibase = g * (WF / 4);              // 64 per group
        float rv0[8], rv1[8];
#pragma unroll
        for (int e = 0; e < 8; ++e) rv0[e] = r2c[(ibase + e) * WF];
#pragma unroll 1
        for (int i0 = ibase; i0 < ibase + WF / 4; i0 += 16) {
#pragma unroll
            for (int e = 0; e < 8; ++e) rv1[e] = r2c[(i0 + 8 + e) * WF];
#pragma unroll
            for (int e = 0; e < 8; ++e) {
                acc0 = fmaf(z1[0][i0 + e], rv0[e], acc0);
                acc1 = fmaf(z1[1][i0 + e], rv0[e], acc1);
            }
            if (i0 + 16 < ibase + WF / 4) {
#pragma unroll
                for (int e = 0; e < 8; ++e) rv0[e] = r2c[(i0 + 16 + e) * WF];
            }
#pragma unroll
            for (int e = 0; e < 8; ++e) {
                acc0 = fmaf(z1[0][i0 + 8 + e], rv1[e], acc0);
                acc1 = fmaf(z1[1][i0 + 8 + e], rv1[e], acc1);
            }
        }
        part[g][0][k] = acc0;
        part[g][1][k] = acc1;
    }
    __syncthreads();
    if (tid < 2 * WF) {
        const int r = tid >> 8;
        const int kk = tid & (WF - 1);
        z2[r][kk] = fmaxf(part[0][r][kk] + part[1][r][kk] +
                          part[2][r][kk] + part[3][r][kk] + rb2[kk], 0.0f);
    }
    __syncthreads();

    // ---- layer 3: outer product + wave reduce (threads 0..511) ------------
    if (tid < 512) {
        const int r    = tid >> 8;      // row 0/1
        const int kk   = tid & (WF - 1);
        const int lane = tid & 63;
        const int wvi  = tid >> 6;      // 0..7
        const float z = z2[r][kk];
        float p[CC];
#pragma unroll
        for (int c = 0; c < CC; ++c) p[c] = z * r3[kk * CC + c];
#pragma unroll
        for (int off = 32; off >= 1; off >>= 1) {
#pragma unroll
            for (int c = 0; c < CC; ++c) p[c] += __shfl_xor(p[c], off, 64);
        }
        if (lane == 0) {
#pragma unroll
            for (int c = 0; c < CC; ++c) red[wvi][c] = p[c];
        }
    }
    __syncthreads();
    if (tid < K3_ROWS * CC) {
        const int r = tid / CC;
        const int c = tid % CC;
        out[(size_t)(b0 + r) * CC + c] =
            red[r * 4 + 0][c] + red[r * 4 + 1][c] +
            red[r * 4 + 2][c] + red[r * 4 + 3][c] + rb3[c];
    }
}

// ---------------------------------------------------------------------------
extern "C" void kernel_launch(void* const* d_in, const int* in_sizes, int n_in,
                              void* d_out, int out_size, void* d_ws, size_t ws_size,
                              hipStream_t stream)
{
    const float* diagms = (const float*)d_in[0];
    // d_in[1] = seg_ids (int32) — structurally n/P with equal counts; unused.
    const float* theta  = (const float*)d_in[2];
    const float* w1     = (const float*)d_in[3];
    const float* b1     = (const float*)d_in[4];
    const float* w2     = (const float*)d_in[5];
    const float* b2     = (const float*)d_in[6];
    const float* w3     = (const float*)d_in[7];
    const float* b3     = (const float*)d_in[8];
    const float* r1     = (const float*)d_in[9];
    const float* rb1    = (const float*)d_in[10];
    const float* r2     = (const float*)d_in[11];
    const float* rb2    = (const float*)d_in[12];
    const float* r3     = (const float*)d_in[13];
    const float* rb3    = (const float*)d_in[14];
    float* out = (float*)d_out;

    float* w_buf  = (float*)d_ws;            // [T*N]
    float* pooled = w_buf + (size_t)TT * NN; // [B, T*Q]

    const int total = TT * NN;               // 716800

    // K1 v3: per-point weight MLP (MFMA, feature-parallel layer 1)
    point_weight_kernel<<<total / 256, 256, 0, stream>>>(
        diagms, w1, b1, w2, b2, w3, b3, w_buf);

    // K2: gaussian rep + segment mean-pool (float4-packed LDS)
    rep_pool_kernel<<<TT * BB, 256, 0, stream>>>(diagms, theta, w_buf, pooled);

    // K3: final rho MLP (TLP-pipelined v3)
    rho_kernel<<<BB / K3_ROWS, 1024, 0, stream>>>(
        pooled, r1, rb1, r2, rb2, r3, rb3, out);
}